// Round 11
// baseline (131.558 us; speedup 1.0000x reference)
//
#include <hip/hip_runtime.h>
#include <hip/hip_bf16.h>

#define R_RES 384
#define S_SEQ 128
#define CM 256
#define CC 32
#define CZ 128

typedef __attribute__((ext_vector_type(8))) short bf16x8;
typedef __attribute__((ext_vector_type(4))) float f32x4;
typedef __attribute__((ext_vector_type(4))) int i32x4;

__device__ __forceinline__ short tobf16(float f) {
    union { __hip_bfloat16 h; short s; } u;
    u.h = __float2bfloat16(f);
    return u.s;
}

// lgkm-only barrier: LDS visibility without draining outstanding global loads
__device__ __forceinline__ void lgkm_barrier() {
    asm volatile("s_waitcnt lgkmcnt(0)" ::: "memory");
    __builtin_amdgcn_s_barrier();
    __builtin_amdgcn_sched_barrier(0);
}

// ---------------- kernel 0a: w_out (1024,128) f32 -> wbTf 16x16x32-B-frag tiled bf16 ------
// frag(z16, k32) lane l: z = z16*16 + (l&15), k = k32*32 + (l>>4)*8 + j
__global__ void k_transpose_wout(const float* __restrict__ w_out, short* __restrict__ wbTf) {
    __shared__ float t[64][65];
    int k0 = blockIdx.x * 64;   // 16 blocks over k=1024
    int z0 = blockIdx.y * 64;   // 2 blocks over z=128
    int tid = threadIdx.x;
    int c = tid & 63, rg = tid >> 6;
#pragma unroll
    for (int rr = 0; rr < 16; ++rr) {
        int kk = rg * 16 + rr;
        t[kk][c] = w_out[(size_t)(k0 + kk) * CZ + z0 + c];
    }
    __syncthreads();
#pragma unroll
    for (int l = 0; l < 2; ++l) {
        int id = l * 256 + tid;
        int f = id >> 6;               // 0..7: z16l = f>>1, k32l = f&1
        int z16l = f >> 1, k32l = f & 1;
        int ln = id & 63;
        int zl = z16l * 16 + (ln & 15);
        int kl = k32l * 32 + (ln >> 4) * 8;
        bf16x8 pk;
#pragma unroll
        for (int j = 0; j < 8; ++j) pk[j] = tobf16(t[kl + j][zl]);
        int z16 = blockIdx.y * 4 + z16l;
        int k32 = blockIdx.x * 2 + k32l;
        *(bf16x8*)(wbTf + ((size_t)(z16 * 32 + k32) * 64 + ln) * 8) = pk;
    }
}

// ---------------- kernel 0b: pack w1|w2 (256,32) -> wcT (64,256) bf16 ----------------
__global__ void k_pack_w12(const float* __restrict__ w1, const float* __restrict__ w2,
                           short* __restrict__ wcT) {
    int idx = blockIdx.x * 256 + threadIdx.x;
    int k = idx >> 6, n = idx & 63;
    float v = (n < 32) ? w1[k * CC + n] : w2[k * CC + (n - 32)];
    wcT[n * CM + k] = tobf16(v);
}

// ---------------- kernel 1: LayerNorm + projections -> aTf, bTf fragment-tiled bf16 ----------------
// aTf frag(fm16, ks32)[lane][8]: m = fm16*16 + (lane&15), s = ks32*32 + (lane>>4)*8 + j
__global__ __launch_bounds__(256) void k_ln_proj(
    const float* __restrict__ M, const float* __restrict__ ln_g, const float* __restrict__ ln_b,
    const float* __restrict__ b1, const float* __restrict__ b2,
    const short* __restrict__ wcT, short* __restrict__ aTf, short* __restrict__ bTf) {
    __shared__ short mnb[64 * 256];      // [s_loc][k] bf16, XOR-swizzled, 32 KB
    __shared__ short ab_s[2][32 * 72];   // [x][s_loc] stride-72 transpose buffers
    int r = blockIdx.x >> 1;
    int s0 = (blockIdx.x & 1) * 64;
    int tid = threadIdx.x, lane = tid & 63, w = tid >> 6;
    int g = lane >> 4, r16 = lane & 15;
    float4 gv = *(const float4*)(ln_g + lane * 4);
    float4 bv = *(const float4*)(ln_b + lane * 4);
    for (int it = 0; it < 16; ++it) {
        int sl = it * 4 + w;
        float4 v = *(const float4*)(M + ((size_t)(s0 + sl) * R_RES + r) * CM + lane * 4);
        float sum = v.x + v.y + v.z + v.w;
        float sq = v.x * v.x + v.y * v.y + v.z * v.z + v.w * v.w;
#pragma unroll
        for (int off = 32; off; off >>= 1) {
            sum += __shfl_xor(sum, off);
            sq  += __shfl_xor(sq, off);
        }
        float mu = sum * (1.0f / 256.0f);
        float var = sq * (1.0f / 256.0f) - mu * mu;
        float rstd = rsqrtf(var + 1e-5f);
        short4 mnp;
        mnp.x = tobf16((v.x - mu) * rstd * gv.x + bv.x);
        mnp.y = tobf16((v.y - mu) * rstd * gv.y + bv.y);
        mnp.z = tobf16((v.z - mu) * rstd * gv.z + bv.z);
        mnp.w = tobf16((v.w - mu) * rstd * gv.w + bv.w);
        int byte = sl * 512 + lane * 8;
        byte ^= ((sl & 7) << 4);
        *(short4*)((char*)mnb + byte) = mnp;
    }
    __syncthreads();
    f32x4 acc[4] = {{0,0,0,0},{0,0,0,0},{0,0,0,0},{0,0,0,0}};
    int srow = w * 16 + r16;
#pragma unroll
    for (int ks = 0; ks < 8; ++ks) {
        int byte = srow * 512 + ks * 64 + g * 16;
        byte ^= ((srow & 7) << 4);
        bf16x8 af = *(const bf16x8*)((const char*)mnb + byte);
#pragma unroll
        for (int nt = 0; nt < 4; ++nt) {
            bf16x8 bf = *(const bf16x8*)(wcT + (nt * 16 + r16) * CM + ks * 32 + g * 8);
            acc[nt] = __builtin_amdgcn_mfma_f32_16x16x32_bf16(af, bf, acc[nt], 0, 0, 0);
        }
    }
#pragma unroll
    for (int nt = 0; nt < 4; ++nt) {
        int n = nt * 16 + r16;
        int x = n & 31, sel = n >> 5;
        float bias = sel ? b2[x] : b1[x];
#pragma unroll
        for (int rr = 0; rr < 4; ++rr) {
            int sl = w * 16 + g * 4 + rr;
            ab_s[sel][x * 72 + sl] = tobf16(acc[nt][rr] + bias);
        }
    }
    __syncthreads();
    // fragment-tiled write-out: fm16 = r*2 + fl, ks32 = (s0>>5) + kl
    int piece = tid >> 6;            // 0..3
    int fl = piece >> 1, kl = piece & 1;
    int ln = tid & 63;
    int x = fl * 16 + (ln & 15);
    int s_loc = kl * 32 + (ln >> 4) * 8;
    i32x4 va = *(const i32x4*)((const char*)ab_s[0] + (x * 72 + s_loc) * 2);
    i32x4 vb = *(const i32x4*)((const char*)ab_s[1] + (x * 72 + s_loc) * 2);
    size_t off = ((((size_t)r * 2 + fl) * 4 + (s0 >> 5) + kl) * 64 + ln) * 16;
    *(i32x4*)((char*)aTf + off) = va;
    *(i32x4*)((char*)bTf + off) = vb;
}

// ---------------- kernel 2: fused outer-product + w_out contraction ----------------
// grid (96 bj, 48 bi), 512 thr (8 waves), O-tile 256(i:8res) x 128(j:4res), LDS 64 KB.
// ph2 wave-grid 4m x 2n: bf from LDS (128KB/tile), af from L2 (x2 dup, coalesced).
// ph4 roles (zh 2 x kq 4): A2-reads 128KB/tile, wbT read exactly once (rolling).
// Pp = 4 f32 slabs [32p][128z] overlaying A2. 2 blocks/CU, 5 barriers.
__global__ __launch_bounds__(512, 4) void k_opm(
    const short* __restrict__ aTf, const short* __restrict__ bTf,
    const short* __restrict__ wbTf, const float* __restrict__ b_out,
    float* __restrict__ out) {
    __shared__ __align__(16) char smem[65536];
    int tid = threadIdx.x, lane = tid & 63, w = tid >> 6;
    int g = lane >> 4, r16 = lane & 15;
    int wm = w & 3, wn = w >> 2;           // ph2 wave grid: 4(m-64) x 2(n-64)
    int bj = blockIdx.x, bi = blockIdx.y;

    // ---- stage B-frags (32 KB, verbatim bTf[bj] region) into smem[0,32K)
    const char* gB = (const char*)bTf + (size_t)bj * 32768;
#pragma unroll
    for (int it = 0; it < 4; ++it) {
        int q = it * 8192 + tid * 16;
        __builtin_amdgcn_global_load_lds(
            (const __attribute__((address_space(1))) void*)(gB + q),
            (__attribute__((address_space(3))) void*)(smem + q), 16, 0, 0);
    }
    // preload af for ks=0 (4 m-frags of this wave's m-block)
    const char* gA = (const char*)aTf + (size_t)bi * 65536;
    bf16x8 afc[4];
#pragma unroll
    for (int mi = 0; mi < 4; ++mi)
        afc[mi] = *(const bf16x8*)(gA + ((wm * 4 + mi) * 4 + 0) * 1024 + lane * 16);
    asm volatile("s_waitcnt vmcnt(0)" ::: "memory");
    __syncthreads();

    // ---- ph2: O[256x128]; acc[mi][ni]: m = (wm*4+mi)*16+r16, n = (wn*4+ni)*16+g*4+rr
    f32x4 acc[4][4] = {};
#pragma unroll
    for (int ks = 0; ks < 4; ++ks) {
        bf16x8 bf[4], afn[4];
#pragma unroll
        for (int ni = 0; ni < 4; ++ni)
            bf[ni] = *(const bf16x8*)(smem + (((wn * 4 + ni) * 4 + ks) * 64 + lane) * 16);
        if (ks < 3) {
#pragma unroll
            for (int mi = 0; mi < 4; ++mi)
                afn[mi] = *(const bf16x8*)(gA + ((wm * 4 + mi) * 4 + ks + 1) * 1024 + lane * 16);
        }
        __builtin_amdgcn_s_setprio(1);
#pragma unroll
        for (int mi = 0; mi < 4; ++mi)
#pragma unroll
            for (int ni = 0; ni < 4; ++ni)
                acc[mi][ni] = __builtin_amdgcn_mfma_f32_16x16x32_bf16(bf[ni], afc[mi], acc[mi][ni], 0, 0, 0);
        __builtin_amdgcn_s_setprio(0);
        if (ks < 3) {
#pragma unroll
            for (int mi = 0; mi < 4; ++mi) afc[mi] = afn[mi];
        }
    }
    lgkm_barrier();   // all B LDS reads done -> smem becomes A2 [0,64K)

    // ---- ph3: O -> A2 bf16 [p = i*4+j][k = x*32+y], dual-XOR swizzle
#pragma unroll
    for (int mi = 0; mi < 4; ++mi)
#pragma unroll
        for (int ni = 0; ni < 4; ++ni) {
            int fm = wm * 4 + mi;
            int fn = wn * 4 + ni;
            int i = fm >> 1, x = (fm & 1) * 16 + r16;
            int j = fn >> 1, y0 = (fn & 1) * 16 + g * 4;
            int p = i * 4 + j;
            int byte = (p * 2048 + x * 64 + y0 * 2) ^ (((p & 7) ^ (x & 7)) << 4);
            short4 pk;
            pk.x = tobf16(acc[mi][ni][0]);
            pk.y = tobf16(acc[mi][ni][1]);
            pk.z = tobf16(acc[mi][ni][2]);
            pk.w = tobf16(acc[mi][ni][3]);
            *(short4*)(smem + byte) = pk;
        }

    // pre-issue wb fragments for kk=0 (global loads survive the lgkm barrier)
    int zh = w & 1, kq = w >> 1;           // ph4 roles: z-half, k-quarter
    bf16x8 wcur[4], wnxt[4];
#pragma unroll
    for (int zi = 0; zi < 4; ++zi)
        wcur[zi] = *(const bf16x8*)(wbTf +
            ((size_t)((zh * 4 + zi) * 32 + kq * 8 + 0) * 64 + lane) * 8);
    lgkm_barrier();   // A2 visible; wb loads in flight

    // ---- ph4: out[32p][128z] partials over k-quarter; rolling wb prefetch
    // c[pf][zi]: p = pf*16 + g*4 + rr, z = zh*64 + zi*16 + r16
    f32x4 c[2][4] = {};
#pragma unroll
    for (int kk = 0; kk < 8; ++kk) {
        int ks = kq * 8 + kk;
        if (kk < 7) {
#pragma unroll
            for (int zi = 0; zi < 4; ++zi)
                wnxt[zi] = *(const bf16x8*)(wbTf +
                    ((size_t)((zh * 4 + zi) * 32 + ks + 1) * 64 + lane) * 8);
        }
        bf16x8 a2f[2];
#pragma unroll
        for (int pf = 0; pf < 2; ++pf) {
            int p = pf * 16 + r16;
            int byte = (p * 2048 + ks * 64 + g * 16) ^ ((((p & 7) ^ (ks & 7))) << 4);
            a2f[pf] = *(const bf16x8*)(smem + byte);
        }
        __builtin_amdgcn_s_setprio(1);
#pragma unroll
        for (int zi = 0; zi < 4; ++zi) {
            c[0][zi] = __builtin_amdgcn_mfma_f32_16x16x32_bf16(a2f[0], wcur[zi], c[0][zi], 0, 0, 0);
            c[1][zi] = __builtin_amdgcn_mfma_f32_16x16x32_bf16(a2f[1], wcur[zi], c[1][zi], 0, 0, 0);
        }
        __builtin_amdgcn_s_setprio(0);
        if (kk < 7) {
#pragma unroll
            for (int zi = 0; zi < 4; ++zi) wcur[zi] = wnxt[zi];
        }
    }
    lgkm_barrier();   // all A2 reads done -> [0,64K) becomes Pp (4 slabs x 16KB)

    // ---- Pp write: slab kq: [32p][128z] f32, addr ^ ((p&7)<<4)
#pragma unroll
    for (int pf = 0; pf < 2; ++pf)
#pragma unroll
        for (int zi = 0; zi < 4; ++zi)
#pragma unroll
            for (int rr = 0; rr < 4; ++rr) {
                int p = pf * 16 + g * 4 + rr;
                int z = zh * 64 + zi * 16 + r16;
                int byte = (kq * 16384 + p * 512 + z * 4) ^ ((p & 7) << 4);
                *(float*)(smem + byte) = c[pf][zi][rr];
            }
    lgkm_barrier();

    // ---- reduce 4 kq-slabs + coalesced f32x4 stores
    {
        int p = tid >> 4;              // 0..31
        int z0 = (tid & 15) * 8;       // 0..120
        int sw = (p & 7) << 4;
        f32x4 s0 = {0, 0, 0, 0}, s1 = {0, 0, 0, 0};
#pragma unroll
        for (int q = 0; q < 4; ++q) {
            int base = q * 16384 + p * 512 + z0 * 4;
            f32x4 u0 = *(const f32x4*)(smem + (base ^ sw));
            f32x4 u1 = *(const f32x4*)(smem + ((base + 16) ^ sw));
            s0 += u0;
            s1 += u1;
        }
        float4 bo0 = *(const float4*)(b_out + z0);
        float4 bo1 = *(const float4*)(b_out + z0 + 4);
        f32x4 r0, r1;
        r0[0] = (s0[0] + bo0.x) * (1.0f / 128.0f);
        r0[1] = (s0[1] + bo0.y) * (1.0f / 128.0f);
        r0[2] = (s0[2] + bo0.z) * (1.0f / 128.0f);
        r0[3] = (s0[3] + bo0.w) * (1.0f / 128.0f);
        r1[0] = (s1[0] + bo1.x) * (1.0f / 128.0f);
        r1[1] = (s1[1] + bo1.y) * (1.0f / 128.0f);
        r1[2] = (s1[2] + bo1.z) * (1.0f / 128.0f);
        r1[3] = (s1[3] + bo1.w) * (1.0f / 128.0f);
        int ig = bi * 8 + (p >> 2);
        int jg = bj * 4 + (p & 3);
        float* po = out + ((size_t)ig * R_RES + jg) * CZ + z0;
        *(f32x4*)(po) = r0;
        *(f32x4*)(po + 4) = r1;
    }
}

extern "C" void kernel_launch(void* const* d_in, const int* in_sizes, int n_in,
                              void* d_out, int out_size, void* d_ws, size_t ws_size,
                              hipStream_t stream) {
    const float* M     = (const float*)d_in[0];
    const float* ln_g  = (const float*)d_in[1];
    const float* ln_b  = (const float*)d_in[2];
    const float* w1    = (const float*)d_in[3];
    const float* b1    = (const float*)d_in[4];
    const float* w2    = (const float*)d_in[5];
    const float* b2    = (const float*)d_in[6];
    const float* w_out = (const float*)d_in[7];
    const float* b_out = (const float*)d_in[8];
    float* out = (float*)d_out;

    short* aTf  = (short*)d_ws;             // 12288 x 128 bf16, fragment-tiled
    short* bTf  = aTf + 12288 * 128;        // 12288 x 128 bf16, fragment-tiled
    short* wbTf = bTf + 12288 * 128;        // 128 x 1024 bf16, 16x16-B-frag tiled
    short* wcT  = wbTf + 128 * 1024;        // 64 x 256 bf16

    k_transpose_wout<<<dim3(16, 2), 256, 0, stream>>>(w_out, wbTf);
    k_pack_w12<<<64, 256, 0, stream>>>(w1, w2, wcT);
    k_ln_proj<<<768, 256, 0, stream>>>(M, ln_g, ln_b, b1, b2, wcT, aTf, bTf);
    k_opm<<<dim3(96, 48), 512, 0, stream>>>(aTf, bTf, wbTf, b_out, out);
}